// Round 2
// baseline (415.349 us; speedup 1.0000x reference)
//
#include <hip/hip_runtime.h>
#include <cmath>

#define EPSF 1e-5f

// ---------------------------------------------------------------------------
// ws float layout (tables only; xd now lives in LDS):
//   W2F  = ws               : float4[15][7][45]  folded stage-2 conv weights (expert innermost)
//   B2F  = W2F + 18900      : float [15][45]     folded stage-2 bias
//   FC2  = W2F + 19576      : float4[2][15][45]  fcw2 re-laid out (expert innermost)
//   FCB2 = FC2 + 5400       : float [2][45]
//   W1F  = FCB2 + 90        : float [20][9]      folded stage-1 conv weights
//   B1F  = W1F + 180        : float [20]
// total = 25266 floats (~101 KB)
// ---------------------------------------------------------------------------

__global__ __launch_bounds__(256) void setup_tables(
    const float* __restrict__ w1, const float* __restrict__ b1,
    const float* __restrict__ g1, const float* __restrict__ be1,
    const float* __restrict__ m1, const float* __restrict__ v1,
    const float* __restrict__ w2, const float* __restrict__ b2,
    const float* __restrict__ g2, const float* __restrict__ be2,
    const float* __restrict__ m2, const float* __restrict__ v2,
    const float* __restrict__ fcw2, const float* __restrict__ fcb2,
    float* __restrict__ ws)
{
  const int t  = blockIdx.x * blockDim.x + threadIdx.x;
  const int nt = gridDim.x * blockDim.x;
  float* W2F  = ws;
  float* B2F  = W2F + 18900;
  float* FC2  = W2F + 19576;
  float* FCB2 = FC2 + 5400;
  float* W1F  = FCB2 + 90;
  float* B1F  = W1F + 180;

  for (int idx = t; idx < 18900; idx += nt) {
    int kk = idx & 3, rest = idx >> 2;
    int e = rest % 45, ok4 = rest / 45;
    int k4 = ok4 % 7, o = ok4 / 7;
    int k = k4 * 4 + kk;
    float s = g2[e*15+o] / sqrtf(v2[e*15+o] + EPSF);
    W2F[idx] = (k < 25) ? w2[(e*15+o)*25 + k] * s : 0.0f;
  }
  for (int idx = t; idx < 675; idx += nt) {
    int e = idx % 45, o = idx / 45;
    float s = g2[e*15+o] / sqrtf(v2[e*15+o] + EPSF);
    B2F[idx] = b2[e*15+o]*s + be2[e*15+o] - m2[e*15+o]*s;
  }
  for (int idx = t; idx < 5400; idx += nt) {
    int kk = idx & 3, rest = idx >> 2;
    int e = rest % 45, t2 = rest / 45;
    int f4 = t2 % 15, oo = t2 / 15;
    FC2[idx] = fcw2[(e*2+oo)*60 + f4*4 + kk];
  }
  for (int idx = t; idx < 90; idx += nt) {
    int e = idx % 45, oo = idx / 45;
    FCB2[idx] = fcb2[e*2+oo];
  }
  for (int idx = t; idx < 180; idx += nt) {
    int ch = idx / 9;
    float s = g1[ch] / sqrtf(v1[ch] + EPSF);
    W1F[idx] = w1[idx] * s;
  }
  for (int idx = t; idx < 20; idx += nt) {
    float s = g1[idx] / sqrtf(v1[idx] + EPSF);
    B1F[idx] = b1[idx]*s + be1[idx] - m1[idx]*s;
  }
}

// component access into float4 array with compile-time index (after unroll)
#define WK4(arr, k) ((k)%4==0 ? arr[(k)/4].x : (k)%4==1 ? arr[(k)/4].y : \
                     (k)%4==2 ? arr[(k)/4].z : arr[(k)/4].w)

// ---------------------------------------------------------------------------
// Fused kernel: block = 64 threads = 64 samples.
// Phase 1: cooperative downscale 28x28 -> 9x9 into LDS (stride 85: conflict-free
//          phase-2 reads since gcd(85,32)=1).
// Phase 2: per-thread tiny net.
// ---------------------------------------------------------------------------
__global__ __launch_bounds__(64) void fused_k(
    const float* __restrict__ x,
    const float* __restrict__ ws,
    const float* __restrict__ fcw1, const float* __restrict__ fcb1,
    float* __restrict__ out, int B)
{
  __shared__ float sxd[64 * 85];
  const int tid = threadIdx.x;
  const int b0  = blockIdx.x * 64;

  // ---- phase 1: downscale ----
  #pragma unroll 1
  for (int it = 0; it < 27; it++) {
    int idx  = it * 64 + tid;       // 0..1727 covers 64 samples x 9 rows x 3 triples
    int trip = idx % 3;
    int r    = (idx / 3) % 9;
    int s    = idx / 27;            // 0..63
    const float* xb = x + (size_t)(b0 + s) * 784;
    float s0 = 0.f, s1 = 0.f, s2 = 0.f;
    #pragma unroll
    for (int dr = 0; dr < 3; dr++) {
      const float* row = xb + (3*r + dr) * 28;
      const float4* rv = reinterpret_cast<const float4*>(row) + 2*trip;
      float4 A = rv[0], Bv = rv[1], Cv = rv[2];
      if (trip == 0)      { s0 += A.x+A.y+A.z;  s1 += A.w+Bv.x+Bv.y;  s2 += Bv.z+Bv.w+Cv.x; }
      else if (trip == 1) { s0 += A.y+A.z+A.w;  s1 += Bv.x+Bv.y+Bv.z; s2 += Bv.w+Cv.x+Cv.y; }
      else                { s0 += A.z+A.w+Bv.x; s1 += Bv.y+Bv.z+Bv.w; s2 += Cv.x+Cv.y+Cv.z; }
    }
    float* xdp = &sxd[s*85 + r*9 + 3*trip];
    xdp[0] = s0 / 9.0f; xdp[1] = s1 / 9.0f; xdp[2] = s2 / 9.0f;
  }
  __syncthreads();

  const int b = b0 + tid;
  if (b >= B) return;

  const float* W2F  = ws;
  const float* B2F  = W2F + 18900;
  const float* FC2  = W2F + 19576;
  const float* FCB2 = FC2 + 5400;
  const float* W1F  = FCB2 + 90;
  const float* B1F  = W1F + 180;

  // ---- xd into registers (conflict-free LDS reads) ----
  float xd[81];
  {
    const float* p = &sxd[tid * 85];
    #pragma unroll
    for (int k = 0; k < 81; k++) xd[k] = p[k];
  }

  // ---- stage 1: 3x3 conv (BN folded) -> relu -> 2x2 maxpool -> fc1 ----
  float logits[10];
  #pragma unroll
  for (int c = 0; c < 10; c++) logits[c] = fcb1[c];

  #pragma unroll 1
  for (int ch = 0; ch < 20; ch++) {
    float w[9];
    #pragma unroll
    for (int k = 0; k < 9; k++) w[k] = W1F[ch*9 + k];
    float bb = B1F[ch];
    float feat[9];
    #pragma unroll
    for (int pr = 0; pr < 3; pr++) {
      #pragma unroll
      for (int pc = 0; pc < 3; pc++) {
        float c00 = bb, c01 = bb, c10 = bb, c11 = bb;
        #pragma unroll
        for (int dr = 0; dr < 3; dr++) {
          #pragma unroll
          for (int dc = 0; dc < 3; dc++) {
            float wk = w[dr*3 + dc];
            c00 = fmaf(xd[(2*pr+0+dr)*9 + 2*pc+0+dc], wk, c00);
            c01 = fmaf(xd[(2*pr+0+dr)*9 + 2*pc+1+dc], wk, c01);
            c10 = fmaf(xd[(2*pr+1+dr)*9 + 2*pc+0+dc], wk, c10);
            c11 = fmaf(xd[(2*pr+1+dr)*9 + 2*pc+1+dc], wk, c11);
          }
        }
        feat[pr*3+pc] = fmaxf(fmaxf(fmaxf(c00, c01), fmaxf(c10, c11)), 0.0f);
      }
    }
    #pragma unroll
    for (int c = 0; c < 10; c++) {
      float acc = logits[c];
      #pragma unroll
      for (int p = 0; p < 9; p++)
        acc = fmaf(feat[p], fcw1[c*180 + ch*9 + p], acc);
      logits[c] = acc;
    }
  }

  // ---- top-2 (stable-argsort tie semantics: later index wins on tie) ----
  int i1 = 0; float v1m = logits[0];
  #pragma unroll
  for (int c = 1; c < 10; c++) { if (logits[c] >= v1m) { v1m = logits[c]; i1 = c; } }
  int i2 = 0; float v2m = -3.0e38f;
  #pragma unroll
  for (int c = 0; c < 10; c++) { if (c != i1 && logits[c] >= v2m) { v2m = logits[c]; i2 = c; } }
  int idx0 = i1 < i2 ? i1 : i2;
  int idx1 = i1 < i2 ? i2 : i1;
  int eid  = 8*idx0 - (idx0*(idx0-1))/2 + idx1 - 1;   // PAIR_TABLE[idx0][idx1]

  float mx = v1m;
  float sume = 0.0f;
  #pragma unroll
  for (int c = 0; c < 10; c++) sume += expf(logits[c] - mx);
  bool use1 = (-logf(sume)) > 0.3f;

  // ---- stage 2: expert 5x5 conv (BN folded) -> relu -> 2x2 pool -> fc2 ----
  const float4* W2F4 = reinterpret_cast<const float4*>(W2F);
  const float4* FC24 = reinterpret_cast<const float4*>(FC2);

  float s2a = FCB2[eid], s2b = FCB2[45 + eid];

  float4 wv[7], fa, fb; float bias;
  #pragma unroll
  for (int k4 = 0; k4 < 7; k4++) wv[k4] = W2F4[k4*45 + eid];
  bias = B2F[eid];
  fa = FC24[eid];
  fb = FC24[15*45 + eid];

  #pragma unroll 1
  for (int o = 0; o < 15; o++) {
    float4 nwv[7], nfa, nfb; float nbias;
    if (o < 14) {   // prefetch next channel; hidden under the 400 FMAs below
      #pragma unroll
      for (int k4 = 0; k4 < 7; k4++) nwv[k4] = W2F4[((o+1)*7 + k4)*45 + eid];
      nbias = B2F[(o+1)*45 + eid];
      nfa = FC24[(o+1)*45 + eid];
      nfb = FC24[(15 + o+1)*45 + eid];
    }
    float feat0 = 0.f, feat1 = 0.f, feat2 = 0.f, feat3 = 0.f;
    #pragma unroll
    for (int ph = 0; ph < 2; ph++) {
      #pragma unroll
      for (int pw = 0; pw < 2; pw++) {
        float c00 = bias, c01 = bias, c10 = bias, c11 = bias;
        #pragma unroll
        for (int i = 0; i < 5; i++) {
          #pragma unroll
          for (int j = 0; j < 5; j++) {
            float wk = WK4(wv, i*5 + j);
            c00 = fmaf(xd[(2*ph+0+i)*9 + 2*pw+0+j], wk, c00);
            c01 = fmaf(xd[(2*ph+0+i)*9 + 2*pw+1+j], wk, c01);
            c10 = fmaf(xd[(2*ph+1+i)*9 + 2*pw+0+j], wk, c10);
            c11 = fmaf(xd[(2*ph+1+i)*9 + 2*pw+1+j], wk, c11);
          }
        }
        float f = fmaxf(fmaxf(fmaxf(c00, c01), fmaxf(c10, c11)), 0.0f);
        if (ph == 0 && pw == 0) feat0 = f;
        else if (ph == 0)       feat1 = f;
        else if (pw == 0)       feat2 = f;
        else                    feat3 = f;
      }
    }
    s2a = fmaf(feat0, fa.x, fmaf(feat1, fa.y, fmaf(feat2, fa.z, fmaf(feat3, fa.w, s2a))));
    s2b = fmaf(feat0, fb.x, fmaf(feat1, fb.y, fmaf(feat2, fb.z, fmaf(feat3, fb.w, s2b))));
    if (o < 14) {
      #pragma unroll
      for (int k4 = 0; k4 < 7; k4++) wv[k4] = nwv[k4];
      bias = nbias; fa = nfa; fb = nfb;
    }
  }

  // ---- scatter + log_softmax ----
  float o10[10];
  #pragma unroll
  for (int c = 0; c < 10; c++) {
    float v = -100.0f;
    v = (c == idx0) ? s2a : v;
    v = (c == idx1) ? s2b : v;
    o10[c] = use1 ? logits[c] : v;
  }
  float m2x = o10[0];
  #pragma unroll
  for (int c = 1; c < 10; c++) m2x = fmaxf(m2x, o10[c]);
  float se2 = 0.0f;
  #pragma unroll
  for (int c = 0; c < 10; c++) se2 += expf(o10[c] - m2x);
  float lse2 = m2x + logf(se2);

  size_t base = (size_t)b * 10;
  #pragma unroll
  for (int c = 0; c < 10; c++) out[base + c] = logits[c];
  #pragma unroll
  for (int c = 0; c < 10; c++) out[(size_t)B*10 + base + c] = o10[c] - lse2;
}

extern "C" void kernel_launch(void* const* d_in, const int* in_sizes, int n_in,
                              void* d_out, int out_size, void* d_ws, size_t ws_size,
                              hipStream_t stream) {
  const float* x    = (const float*)d_in[0];
  const float* w1   = (const float*)d_in[1];
  const float* b1   = (const float*)d_in[2];
  const float* g1   = (const float*)d_in[3];
  const float* be1  = (const float*)d_in[4];
  const float* m1   = (const float*)d_in[5];
  const float* v1   = (const float*)d_in[6];
  const float* fcw1 = (const float*)d_in[7];
  const float* fcb1 = (const float*)d_in[8];
  const float* w2   = (const float*)d_in[9];
  const float* b2   = (const float*)d_in[10];
  const float* g2   = (const float*)d_in[11];
  const float* be2  = (const float*)d_in[12];
  const float* m2   = (const float*)d_in[13];
  const float* v2   = (const float*)d_in[14];
  const float* fcw2 = (const float*)d_in[15];
  const float* fcb2 = (const float*)d_in[16];
  float* out = (float*)d_out;
  float* ws  = (float*)d_ws;
  const int B = in_sizes[0] / 784;

  setup_tables<<<80, 256, 0, stream>>>(w1, b1, g1, be1, m1, v1,
                                       w2, b2, g2, be2, m2, v2, fcw2, fcb2, ws);
  fused_k<<<(B + 63)/64, 64, 0, stream>>>(x, ws, fcw1, fcb1, out, B);
}

// Round 3
// 369.486 us; speedup vs baseline: 1.1241x; 1.1241x over previous
//
#include <hip/hip_runtime.h>
#include <cmath>

#define EPSF 1e-5f

// ---------------------------------------------------------------------------
// ws float layout (tables only):
//   W2F  = ws               : float4[15][7][45]  folded stage-2 conv weights (expert innermost)
//   B2F  = W2F + 18900      : float [15][45]     folded stage-2 bias
//   FC2  = W2F + 19576      : float4[2][15][45]  fcw2 re-laid out (expert innermost)
//   FCB2 = FC2 + 5400       : float [2][45]
//   W1F  = FCB2 + 90        : float [20][9]      folded stage-1 conv weights
//   B1F  = W1F + 180        : float [20]
// total = 25266 floats (~101 KB)
// ---------------------------------------------------------------------------

__global__ __launch_bounds__(256) void setup_tables(
    const float* __restrict__ w1, const float* __restrict__ b1,
    const float* __restrict__ g1, const float* __restrict__ be1,
    const float* __restrict__ m1, const float* __restrict__ v1,
    const float* __restrict__ w2, const float* __restrict__ b2,
    const float* __restrict__ g2, const float* __restrict__ be2,
    const float* __restrict__ m2, const float* __restrict__ v2,
    const float* __restrict__ fcw2, const float* __restrict__ fcb2,
    float* __restrict__ ws)
{
  const int t  = blockIdx.x * blockDim.x + threadIdx.x;
  const int nt = gridDim.x * blockDim.x;
  float* W2F  = ws;
  float* B2F  = W2F + 18900;
  float* FC2  = W2F + 19576;
  float* FCB2 = FC2 + 5400;
  float* W1F  = FCB2 + 90;
  float* B1F  = W1F + 180;

  for (int idx = t; idx < 18900; idx += nt) {
    int kk = idx & 3, rest = idx >> 2;
    int e = rest % 45, ok4 = rest / 45;
    int k4 = ok4 % 7, o = ok4 / 7;
    int k = k4 * 4 + kk;
    float s = g2[e*15+o] / sqrtf(v2[e*15+o] + EPSF);
    W2F[idx] = (k < 25) ? w2[(e*15+o)*25 + k] * s : 0.0f;
  }
  for (int idx = t; idx < 675; idx += nt) {
    int e = idx % 45, o = idx / 45;
    float s = g2[e*15+o] / sqrtf(v2[e*15+o] + EPSF);
    B2F[idx] = b2[e*15+o]*s + be2[e*15+o] - m2[e*15+o]*s;
  }
  for (int idx = t; idx < 5400; idx += nt) {
    int kk = idx & 3, rest = idx >> 2;
    int e = rest % 45, t2 = rest / 45;
    int f4 = t2 % 15, oo = t2 / 15;
    FC2[idx] = fcw2[(e*2+oo)*60 + f4*4 + kk];
  }
  for (int idx = t; idx < 90; idx += nt) {
    int e = idx % 45, oo = idx / 45;
    FCB2[idx] = fcb2[e*2+oo];
  }
  for (int idx = t; idx < 180; idx += nt) {
    int ch = idx / 9;
    float s = g1[ch] / sqrtf(v1[ch] + EPSF);
    W1F[idx] = w1[idx] * s;
  }
  for (int idx = t; idx < 20; idx += nt) {
    float s = g1[idx] / sqrtf(v1[idx] + EPSF);
    B1F[idx] = b1[idx]*s + be1[idx] - m1[idx]*s;
  }
}

// component access into float4 array with compile-time index (after unroll)
#define GETC(arr, k) ((k)%4==0 ? arr[(k)/4].x : (k)%4==1 ? arr[(k)/4].y : \
                      (k)%4==2 ? arr[(k)/4].z : arr[(k)/4].w)

// ---------------------------------------------------------------------------
// Fused kernel: 1 thread = 1 sample, everything in registers.
// __launch_bounds__(64,1): 1 wave/SIMD target -> full 512-VGPR budget, no spills.
// (grid is 1024 waves on 1024 SIMDs, so higher occupancy is unreachable anyway)
// ---------------------------------------------------------------------------
__global__ __launch_bounds__(64, 1) void fused_k(
    const float* __restrict__ x,
    const float* __restrict__ ws,
    const float* __restrict__ fcw1, const float* __restrict__ fcb1,
    float* __restrict__ out, int B)
{
  const int b = blockIdx.x * 64 + threadIdx.x;
  if (b >= B) return;

  const float* W2F  = ws;
  const float* B2F  = W2F + 18900;
  const float* FC2  = W2F + 19576;
  const float* FCB2 = FC2 + 5400;
  const float* W1F  = FCB2 + 90;
  const float* B1F  = W1F + 180;

  // ---- downscale 28x28 -> 9x9 straight into registers ----
  // lane reads its own sample: per instruction, 64 lanes touch 64 lines
  // (stride 3136 B) but consecutive unrolled loads reuse each line fully.
  float xd[81];
  const float* xb = x + (size_t)b * 784;
  #pragma unroll
  for (int r = 0; r < 9; r++) {
    float4 rowv[3][7];
    #pragma unroll
    for (int dr = 0; dr < 3; dr++) {
      const float4* rv = reinterpret_cast<const float4*>(xb + (3*r + dr) * 28);
      #pragma unroll
      for (int q = 0; q < 7; q++) rowv[dr][q] = rv[q];
    }
    #pragma unroll
    for (int c = 0; c < 9; c++) {
      float s = 0.0f;
      #pragma unroll
      for (int dr = 0; dr < 3; dr++)
        s += GETC(rowv[dr], 3*c) + GETC(rowv[dr], 3*c+1) + GETC(rowv[dr], 3*c+2);
      xd[r*9 + c] = s * (1.0f / 9.0f);
    }
  }

  // ---- stage 1: 3x3 conv (BN folded) -> relu -> 2x2 maxpool -> fc1 ----
  float logits[10];
  #pragma unroll
  for (int c = 0; c < 10; c++) logits[c] = fcb1[c];

  #pragma unroll 1
  for (int ch = 0; ch < 20; ch++) {
    float w[9];
    #pragma unroll
    for (int k = 0; k < 9; k++) w[k] = W1F[ch*9 + k];
    float bb = B1F[ch];
    float feat[9];
    #pragma unroll
    for (int pr = 0; pr < 3; pr++) {
      #pragma unroll
      for (int pc = 0; pc < 3; pc++) {
        float c00 = bb, c01 = bb, c10 = bb, c11 = bb;
        #pragma unroll
        for (int dr = 0; dr < 3; dr++) {
          #pragma unroll
          for (int dc = 0; dc < 3; dc++) {
            float wk = w[dr*3 + dc];
            c00 = fmaf(xd[(2*pr+0+dr)*9 + 2*pc+0+dc], wk, c00);
            c01 = fmaf(xd[(2*pr+0+dr)*9 + 2*pc+1+dc], wk, c01);
            c10 = fmaf(xd[(2*pr+1+dr)*9 + 2*pc+0+dc], wk, c10);
            c11 = fmaf(xd[(2*pr+1+dr)*9 + 2*pc+1+dc], wk, c11);
          }
        }
        feat[pr*3+pc] = fmaxf(fmaxf(fmaxf(c00, c01), fmaxf(c10, c11)), 0.0f);
      }
    }
    #pragma unroll
    for (int c = 0; c < 10; c++) {
      float acc = logits[c];
      #pragma unroll
      for (int p = 0; p < 9; p++)
        acc = fmaf(feat[p], fcw1[c*180 + ch*9 + p], acc);
      logits[c] = acc;
    }
  }

  // ---- top-2 (stable-argsort tie semantics: later index wins on tie) ----
  int i1 = 0; float v1m = logits[0];
  #pragma unroll
  for (int c = 1; c < 10; c++) { if (logits[c] >= v1m) { v1m = logits[c]; i1 = c; } }
  int i2 = 0; float v2m = -3.0e38f;
  #pragma unroll
  for (int c = 0; c < 10; c++) { if (c != i1 && logits[c] >= v2m) { v2m = logits[c]; i2 = c; } }
  int idx0 = i1 < i2 ? i1 : i2;
  int idx1 = i1 < i2 ? i2 : i1;
  int eid  = 8*idx0 - (idx0*(idx0-1))/2 + idx1 - 1;   // PAIR_TABLE[idx0][idx1]

  float mx = v1m;
  float sume = 0.0f;
  #pragma unroll
  for (int c = 0; c < 10; c++) sume += expf(logits[c] - mx);
  bool use1 = (-logf(sume)) > 0.3f;

  // ---- stage 2: expert 5x5 conv (BN folded) -> relu -> 2x2 pool -> fc2 ----
  const float4* W2F4 = reinterpret_cast<const float4*>(W2F);
  const float4* FC24 = reinterpret_cast<const float4*>(FC2);

  float s2a = FCB2[eid], s2b = FCB2[45 + eid];

  float4 wv[7], fa, fb; float bias;
  #pragma unroll
  for (int k4 = 0; k4 < 7; k4++) wv[k4] = W2F4[k4*45 + eid];
  bias = B2F[eid];
  fa = FC24[eid];
  fb = FC24[15*45 + eid];

  #pragma unroll 1
  for (int o = 0; o < 15; o++) {
    float4 nwv[7], nfa, nfb; float nbias;
    if (o < 14) {   // prefetch next channel; hidden under the 400 FMAs below
      #pragma unroll
      for (int k4 = 0; k4 < 7; k4++) nwv[k4] = W2F4[((o+1)*7 + k4)*45 + eid];
      nbias = B2F[(o+1)*45 + eid];
      nfa = FC24[(o+1)*45 + eid];
      nfb = FC24[(15 + o+1)*45 + eid];
    }
    float feat0 = 0.f, feat1 = 0.f, feat2 = 0.f, feat3 = 0.f;
    #pragma unroll
    for (int ph = 0; ph < 2; ph++) {
      #pragma unroll
      for (int pw = 0; pw < 2; pw++) {
        float c00 = bias, c01 = bias, c10 = bias, c11 = bias;
        #pragma unroll
        for (int i = 0; i < 5; i++) {
          #pragma unroll
          for (int j = 0; j < 5; j++) {
            float wk = GETC(wv, i*5 + j);
            c00 = fmaf(xd[(2*ph+0+i)*9 + 2*pw+0+j], wk, c00);
            c01 = fmaf(xd[(2*ph+0+i)*9 + 2*pw+1+j], wk, c01);
            c10 = fmaf(xd[(2*ph+1+i)*9 + 2*pw+0+j], wk, c10);
            c11 = fmaf(xd[(2*ph+1+i)*9 + 2*pw+1+j], wk, c11);
          }
        }
        float f = fmaxf(fmaxf(fmaxf(c00, c01), fmaxf(c10, c11)), 0.0f);
        if (ph == 0 && pw == 0) feat0 = f;
        else if (ph == 0)       feat1 = f;
        else if (pw == 0)       feat2 = f;
        else                    feat3 = f;
      }
    }
    s2a = fmaf(feat0, fa.x, fmaf(feat1, fa.y, fmaf(feat2, fa.z, fmaf(feat3, fa.w, s2a))));
    s2b = fmaf(feat0, fb.x, fmaf(feat1, fb.y, fmaf(feat2, fb.z, fmaf(feat3, fb.w, s2b))));
    if (o < 14) {
      #pragma unroll
      for (int k4 = 0; k4 < 7; k4++) wv[k4] = nwv[k4];
      bias = nbias; fa = nfa; fb = nfb;
    }
  }

  // ---- scatter + log_softmax ----
  float o10[10];
  #pragma unroll
  for (int c = 0; c < 10; c++) {
    float v = -100.0f;
    v = (c == idx0) ? s2a : v;
    v = (c == idx1) ? s2b : v;
    o10[c] = use1 ? logits[c] : v;
  }
  float m2x = o10[0];
  #pragma unroll
  for (int c = 1; c < 10; c++) m2x = fmaxf(m2x, o10[c]);
  float se2 = 0.0f;
  #pragma unroll
  for (int c = 0; c < 10; c++) se2 += expf(o10[c] - m2x);
  float lse2 = m2x + logf(se2);

  size_t base = (size_t)b * 10;
  #pragma unroll
  for (int c = 0; c < 10; c++) out[base + c] = logits[c];
  #pragma unroll
  for (int c = 0; c < 10; c++) out[(size_t)B*10 + base + c] = o10[c] - lse2;
}

extern "C" void kernel_launch(void* const* d_in, const int* in_sizes, int n_in,
                              void* d_out, int out_size, void* d_ws, size_t ws_size,
                              hipStream_t stream) {
  const float* x    = (const float*)d_in[0];
  const float* w1   = (const float*)d_in[1];
  const float* b1   = (const float*)d_in[2];
  const float* g1   = (const float*)d_in[3];
  const float* be1  = (const float*)d_in[4];
  const float* m1   = (const float*)d_in[5];
  const float* v1   = (const float*)d_in[6];
  const float* fcw1 = (const float*)d_in[7];
  const float* fcb1 = (const float*)d_in[8];
  const float* w2   = (const float*)d_in[9];
  const float* b2   = (const float*)d_in[10];
  const float* g2   = (const float*)d_in[11];
  const float* be2  = (const float*)d_in[12];
  const float* m2   = (const float*)d_in[13];
  const float* v2   = (const float*)d_in[14];
  const float* fcw2 = (const float*)d_in[15];
  const float* fcb2 = (const float*)d_in[16];
  float* out = (float*)d_out;
  float* ws  = (float*)d_ws;
  const int B = in_sizes[0] / 784;

  setup_tables<<<80, 256, 0, stream>>>(w1, b1, g1, be1, m1, v1,
                                       w2, b2, g2, be2, m2, v2, fcw2, fcb2, ws);
  fused_k<<<(B + 63)/64, 64, 0, stream>>>(x, ws, fcw1, fcb1, out, B);
}